// Round 6
// baseline (84.516 us; speedup 1.0000x reference)
//
#include <hip/hip_runtime.h>
#include <hip/hip_bf16.h>
#include <math.h>

#define NF    50              // n_frequencies
#define NFH   (NF / 2)        // freqs per wave-half
#define DEMB  10              // embedding dim
#define W1G   (4 * NF * DEMB) // 2000 floats of w1 per gene
#define MAXG  512             // max genes supported by sort path

#define HTPB   256
#define HCHUNK 4096
#define HFPT   (HCHUNK / HTPB) // 16 fragments per thread in hist/scatter

// ---------------------------------------------------------------------------
// K1: per-block private histogram rows (no global atomics) + out init with b2
// ---------------------------------------------------------------------------
__global__ __launch_bounds__(HTPB) void hist_init_k(
    const int* __restrict__ gm, int n_frag, int n_genes,
    int* __restrict__ counts_mat,                 // [gridDim.x][MAXG]
    float* __restrict__ out, const float* __restrict__ b2,
    const int* __restrict__ genes_oi, int gene_n, int total)
{
    __shared__ int lcnt[MAXG];
    for (int t = threadIdx.x; t < MAXG; t += HTPB) lcnt[t] = 0;
    __syncthreads();

    int base = blockIdx.x * HCHUNK;
#pragma unroll
    for (int j = 0; j < HFPT; ++j) {
        int f = base + j * HTPB + (int)threadIdx.x;
        if (f < n_frag) atomicAdd(&lcnt[gm[f]], 1);
    }

    // init out with broadcast b2 (grid-stride; independent of hist)
    int nthreads = gridDim.x * HTPB;
    for (int i = blockIdx.x * HTPB + (int)threadIdx.x; i < total; i += nthreads) {
        int col = (int)((unsigned)i % (unsigned)gene_n);
        out[i] = b2[genes_oi[col]];
    }

    __syncthreads();
    int* row = counts_mat + (size_t)blockIdx.x * MAXG;
    for (int t = threadIdx.x; t < MAXG; t += HTPB) row[t] = lcnt[t];
}

// ---------------------------------------------------------------------------
// K2: reduce count matrix; scan of 64-PADDED counts; build wave->gene table.
// po[g] = padded exclusive start, cnt[g] = true count, w2g[w] = gene of wave w
// ---------------------------------------------------------------------------
__global__ void scan_k(const int* __restrict__ counts_mat, int nblk,
                       int* __restrict__ po, int* __restrict__ cursor,
                       int* __restrict__ cnt, int* __restrict__ w2g,
                       int n_genes, int wmax)
{
    __shared__ int buf[MAXG];
    int tid = threadIdx.x;
    int s = 0;
#pragma unroll 8
    for (int b = 0; b < nblk; ++b) s += counts_mat[(size_t)b * MAXG + tid];
    int pc = ((s + 63) >> 6) << 6;       // padded count
    buf[tid] = pc;
    __syncthreads();
    for (int d = 1; d < MAXG; d <<= 1) {
        int t = (tid >= d) ? buf[tid - d] : 0;
        __syncthreads();
        buf[tid] += t;
        __syncthreads();
    }
    int incl = buf[tid];
    if (tid < n_genes) {
        po[tid + 1] = incl;
        cursor[tid] = incl - pc;         // padded exclusive start
        cnt[tid]    = s;
        // wave table for this gene
        int wbeg = (incl - pc) >> 6;
        int wend = incl >> 6;
        for (int w = wbeg; w < wend; ++w) w2g[w] = tid;
    }
    if (tid == 0) po[0] = 0;
    __syncthreads();
    int W = buf[n_genes - 1] >> 6;       // total frag-waves
    for (int w = W + tid; w < wmax; w += MAXG) w2g[w] = -1;
}

// ---------------------------------------------------------------------------
// K3: scatter packed records (coords, bin) into padded gene-sorted order.
// ---------------------------------------------------------------------------
__global__ __launch_bounds__(HTPB) void scatter_k(
    const int* __restrict__ gm, const float* __restrict__ coords,
    const int* __restrict__ lcg, int* __restrict__ cursor,
    float* __restrict__ xs, int* __restrict__ bins,
    int n_frag, int n_genes)
{
    __shared__ int lcnt[MAXG];
    __shared__ int lbase[MAXG];
    for (int t = threadIdx.x; t < MAXG; t += HTPB) lcnt[t] = 0;
    __syncthreads();

    int base = blockIdx.x * HCHUNK;
    int g[HFPT], lr[HFPT];
#pragma unroll
    for (int j = 0; j < HFPT; ++j) {
        int f = base + j * HTPB + (int)threadIdx.x;
        if (f < n_frag) {
            g[j]  = gm[f];
            lr[j] = atomicAdd(&lcnt[g[j]], 1);
        } else {
            g[j] = -1;
        }
    }
    __syncthreads();
    for (int t = threadIdx.x; t < MAXG; t += HTPB) {
        int c = lcnt[t];
        lbase[t] = c ? atomicAdd(&cursor[t], c) : 0;
    }
    __syncthreads();
#pragma unroll
    for (int j = 0; j < HFPT; ++j) {
        if (g[j] >= 0) {
            int f = base + j * HTPB + (int)threadIdx.x;
            int pos = lbase[g[j]] + lr[j];
            float2 xy = ((const float2*)coords)[f];
            xs[2 * pos + 0] = xy.x;
            xs[2 * pos + 1] = xy.y;
            bins[pos] = lcg[f];
        }
    }
}

// ---------------------------------------------------------------------------
// K4: main — gene-uniform WAVES over the padded sorted array; freq dimension
// split across a wave pair (khalf 0/1), combined via LDS. Weights fetched
// through the SCALAR pipe (readfirstlane'd gene -> s_load), no LDS staging.
// Block = 256 threads = 2 frag-groups x 2 freq-halves.
// ---------------------------------------------------------------------------
__global__ __launch_bounds__(256) void main_k(
    const float* __restrict__ w1, const float* __restrict__ b1,
    const float* __restrict__ w2, const int* __restrict__ genes_oi,
    const float* __restrict__ xs, const int* __restrict__ bins,
    const int* __restrict__ po, const int* __restrict__ cnt,
    const int* __restrict__ w2g, float* __restrict__ out,
    int gene_n, int wmax)
{
    __shared__ float fr[NF];
    __shared__ float hpart[2][64][DEMB + 1];   // khalf=1 partials, padded

    if (threadIdx.x < NF) {
        float ex = (-2.0f * (float)(threadIdx.x + 1) / (float)NF) * 9.965784284662087f;
        fr[threadIdx.x] = exp2f(ex) * 0.15915494309189535f;  // base/(2*pi)
    }
    __syncthreads();

    int grp   = threadIdx.x >> 7;         // frag group in block (0/1)
    int khalf = (threadIdx.x >> 6) & 1;   // freq half (0/1)
    int lane  = threadIdx.x & 63;
    int fw    = blockIdx.x * 2 + grp;     // frag-wave index

    int g = (fw < wmax) ? w2g[fw] : -1;
    g = __builtin_amdgcn_readfirstlane(g);
    bool active = (g >= 0);

    float h[DEMB];
#pragma unroll
    for (int d = 0; d < DEMB; ++d) h[d] = 0.0f;

    int  pos   = fw * 64 + lane;
    bool valid = false;
    float2 xy  = make_float2(0.0f, 0.0f);

    if (active) {
        int start = po[g];
        int count = cnt[g];
        valid = (pos - start) < count;
        if (valid) xy = ((const float2*)xs)[pos];

        const float* wrow = w1 + (size_t)g * W1G;
        if (khalf == 0) {
            const float* b1row = b1 + (size_t)g * DEMB;
#pragma unroll
            for (int d = 0; d < DEMB; ++d) h[d] = b1row[d];
        }

        int i0 = khalf * NFH;
#pragma unroll 5
        for (int i = i0; i < i0 + NFH; ++i) {
            float fv = fr[i];
            float r0 = xy.x * fv; r0 -= rintf(r0);
            float r1 = xy.y * fv; r1 -= rintf(r1);
            float s0 = __builtin_amdgcn_sinf(r0);
            float c0 = __builtin_amdgcn_cosf(r0);
            float s1 = __builtin_amdgcn_sinf(r1);
            float c1 = __builtin_amdgcn_cosf(r1);
            const float* wa = wrow + (2 * i) * DEMB;            // rows 2i, 2i+1
            const float* wb = wrow + (2 * NF + 2 * i) * DEMB;   // coord-1 rows
#pragma unroll
            for (int d = 0; d < DEMB; ++d) {
                h[d] += s0 * wa[d] + c0 * wa[DEMB + d] + s1 * wb[d] + c1 * wb[DEMB + d];
            }
        }

        if (khalf == 1) {
#pragma unroll
            for (int d = 0; d < DEMB; ++d) hpart[grp][lane][d] = h[d];
        }
    }
    __syncthreads();

    if (active && khalf == 0 && valid) {
        int bin = bins[pos];
        int col = (int)((unsigned)bin % (unsigned)gene_n);
        const float* w2row = w2 + (size_t)genes_oi[col] * DEMB;
        float sum = 0.0f;
#pragma unroll
        for (int d = 0; d < DEMB; ++d) {
            float hv = h[d] + hpart[grp][lane][d];
            float sg = 1.0f / (1.0f + __expf(-hv));
            sum += sg * w2row[d];
        }
        atomicAdd(&out[bin], sum);
    }
}

// ---------------------------------------------------------------------------
// Fallback (workspace too small): one thread per fragment, non-uniform gene
// ---------------------------------------------------------------------------
__global__ __launch_bounds__(256) void frag_naive_k(
    const float* __restrict__ coords, const float* __restrict__ w1,
    const float* __restrict__ b1, const float* __restrict__ w2,
    const int* __restrict__ gm, const int* __restrict__ lcg,
    const int* __restrict__ genes_oi, float* __restrict__ out,
    int gene_n, int n_frag)
{
    __shared__ float fr[NF];
    if (threadIdx.x < NF) {
        float ex = (-2.0f * (float)(threadIdx.x + 1) / (float)NF) * 9.965784284662087f;
        fr[threadIdx.x] = exp2f(ex) * 0.15915494309189535f;
    }
    __syncthreads();

    int f = blockIdx.x * blockDim.x + threadIdx.x;
    if (f >= n_frag) return;
    int g = gm[f];
    const float* wrow  = w1 + (size_t)g * W1G;
    const float* b1row = b1 + (size_t)g * DEMB;
    float x0 = coords[2 * f + 0];
    float x1 = coords[2 * f + 1];

    float h[DEMB];
#pragma unroll
    for (int d = 0; d < DEMB; ++d) h[d] = b1row[d];
#pragma unroll 2
    for (int i = 0; i < NF; ++i) {
        float fv = fr[i];
        float r0 = x0 * fv; r0 -= rintf(r0);
        float r1 = x1 * fv; r1 -= rintf(r1);
        float s0 = __builtin_amdgcn_sinf(r0), c0 = __builtin_amdgcn_cosf(r0);
        float s1 = __builtin_amdgcn_sinf(r1), c1 = __builtin_amdgcn_cosf(r1);
        const float* wa = wrow + (2 * i) * DEMB;
        const float* wb = wrow + (2 * NF + 2 * i) * DEMB;
#pragma unroll
        for (int d = 0; d < DEMB; ++d) {
            h[d] += s0 * wa[d] + c0 * wa[DEMB + d] + s1 * wb[d] + c1 * wb[DEMB + d];
        }
    }
    int bin = lcg[f];
    int col = (int)((unsigned)bin % (unsigned)gene_n);
    const float* w2row = w2 + (size_t)genes_oi[col] * DEMB;
    float sum = 0.0f;
#pragma unroll
    for (int d = 0; d < DEMB; ++d) {
        float sg = 1.0f / (1.0f + __expf(-h[d]));
        sum += sg * w2row[d];
    }
    atomicAdd(&out[bin], sum);
}

__global__ void init_out_k(float* __restrict__ out, const float* __restrict__ b2,
                           const int* __restrict__ genes_oi, int gene_n, int total)
{
    int i = blockIdx.x * blockDim.x + threadIdx.x;
    if (i < total) {
        int col = (int)((unsigned)i % (unsigned)gene_n);
        out[i] = b2[genes_oi[col]];
    }
}

// ---------------------------------------------------------------------------
extern "C" void kernel_launch(void* const* d_in, const int* in_sizes, int n_in,
                              void* d_out, int out_size, void* d_ws, size_t ws_size,
                              hipStream_t stream)
{
    const float* coords   = (const float*)d_in[0];
    const float* w1       = (const float*)d_in[1];
    const float* b1       = (const float*)d_in[2];
    const float* w2       = (const float*)d_in[3];
    const float* b2       = (const float*)d_in[4];
    const int*   gm       = (const int*)d_in[5];
    const int*   lcg      = (const int*)d_in[6];
    const int*   genes_oi = (const int*)d_in[7];

    int n_frag  = in_sizes[5];
    int n_genes = in_sizes[4];
    int gene_n  = in_sizes[7];
    int total   = out_size;
    float* out  = (float*)d_out;

    int nblk = (n_frag + HCHUNK - 1) / HCHUNK;
    int wmax = (n_frag >> 6) + n_genes + 1;            // upper bound on frag-waves
    size_t padcap = (size_t)n_frag + 64 * (size_t)n_genes + 64;

    // workspace layout
    int* counts_mat = (int*)d_ws;                          // [nblk][MAXG]
    int* po         = counts_mat + (size_t)nblk * MAXG;    // [MAXG+1]
    int* cursor     = po + (MAXG + 1);                     // [MAXG]
    int* cnt        = cursor + MAXG;                       // [MAXG]
    int* w2g        = cnt + MAXG;                          // [wmax]
    float* xs       = (float*)(w2g + wmax);                // [2*padcap]
    int* bins       = (int*)(xs + 2 * padcap);             // [padcap]
    size_t need = ((size_t)nblk * MAXG + (MAXG + 1) + 2 * MAXG + wmax
                   + 3 * padcap) * sizeof(int);

    bool use_sorted = (ws_size >= need) && (n_genes <= MAXG);
    if (use_sorted) {
        hist_init_k<<<nblk, HTPB, 0, stream>>>(gm, n_frag, n_genes, counts_mat,
                                               out, b2, genes_oi, gene_n, total);
        scan_k<<<1, MAXG, 0, stream>>>(counts_mat, nblk, po, cursor, cnt, w2g,
                                       n_genes, wmax);
        scatter_k<<<nblk, HTPB, 0, stream>>>(gm, coords, lcg, cursor,
                                             xs, bins, n_frag, n_genes);
        int mblk = (wmax + 1) / 2;
        main_k<<<mblk, 256, 0, stream>>>(w1, b1, w2, genes_oi, xs, bins,
                                         po, cnt, w2g, out, gene_n, wmax);
    } else {
        init_out_k<<<(total + 255) / 256, 256, 0, stream>>>(out, b2, genes_oi, gene_n, total);
        frag_naive_k<<<(n_frag + 255) / 256, 256, 0, stream>>>(coords, w1, b1, w2, gm, lcg,
                                                               genes_oi, out, gene_n, n_frag);
    }
}

// Round 7
// 51.670 us; speedup vs baseline: 1.6357x; 1.6357x over previous
//
#include <hip/hip_runtime.h>
#include <hip/hip_bf16.h>
#include <math.h>

#define NF    50              // n_frequencies
#define DEMB  10              // embedding dim
#define W1G   (4 * NF * DEMB) // 2000 floats of w1 per gene
#define MAXG  512             // max genes supported by sort path

#define HTPB   256
#define HCHUNK 4096
#define HFPT   (HCHUNK / HTPB) // 16 fragments per thread in hist/scatter

typedef __attribute__((ext_vector_type(8))) short short8v;  // 8 bf16
typedef __attribute__((ext_vector_type(4))) float f32x4v;

__device__ __forceinline__ short f2bf(float f) {
    unsigned u = __float_as_uint(f);
    u += 0x7fffu + ((u >> 16) & 1u);    // RNE
    return (short)(u >> 16);
}

// ---------------------------------------------------------------------------
// K1: per-block private histogram rows (no global atomics) + out init with b2
// ---------------------------------------------------------------------------
__global__ __launch_bounds__(HTPB) void hist_init_k(
    const int* __restrict__ gm, int n_frag, int n_genes,
    int* __restrict__ counts_mat,                 // [gridDim.x][MAXG]
    float* __restrict__ out, const float* __restrict__ b2,
    const int* __restrict__ genes_oi, int gene_n, int total)
{
    __shared__ int lcnt[MAXG];
    for (int t = threadIdx.x; t < MAXG; t += HTPB) lcnt[t] = 0;
    __syncthreads();

    int base = blockIdx.x * HCHUNK;
#pragma unroll
    for (int j = 0; j < HFPT; ++j) {
        int f = base + j * HTPB + (int)threadIdx.x;
        if (f < n_frag) atomicAdd(&lcnt[gm[f]], 1);
    }

    int nthreads = gridDim.x * HTPB;
    for (int i = blockIdx.x * HTPB + (int)threadIdx.x; i < total; i += nthreads) {
        int col = (int)((unsigned)i % (unsigned)gene_n);
        out[i] = b2[genes_oi[col]];
    }

    __syncthreads();
    int* row = counts_mat + (size_t)blockIdx.x * MAXG;
    for (int t = threadIdx.x; t < MAXG; t += HTPB) row[t] = lcnt[t];
}

// ---------------------------------------------------------------------------
// K2: reduce count matrix; scan of 64-PADDED counts; build wave->gene table.
// ---------------------------------------------------------------------------
__global__ void scan_k(const int* __restrict__ counts_mat, int nblk,
                       int* __restrict__ po, int* __restrict__ cursor,
                       int* __restrict__ cnt, int* __restrict__ w2g,
                       int n_genes, int wmax)
{
    __shared__ int buf[MAXG];
    int tid = threadIdx.x;
    int s = 0;
#pragma unroll 8
    for (int b = 0; b < nblk; ++b) s += counts_mat[(size_t)b * MAXG + tid];
    int pc = ((s + 63) >> 6) << 6;       // padded count
    buf[tid] = pc;
    __syncthreads();
    for (int d = 1; d < MAXG; d <<= 1) {
        int t = (tid >= d) ? buf[tid - d] : 0;
        __syncthreads();
        buf[tid] += t;
        __syncthreads();
    }
    int incl = buf[tid];
    if (tid < n_genes) {
        po[tid + 1] = incl;
        cursor[tid] = incl - pc;
        cnt[tid]    = s;
        int wbeg = (incl - pc) >> 6;
        int wend = incl >> 6;
        for (int w = wbeg; w < wend; ++w) w2g[w] = tid;
    }
    if (tid == 0) po[0] = 0;
    __syncthreads();
    int W = buf[n_genes - 1] >> 6;
    for (int w = W + tid; w < wmax; w += MAXG) w2g[w] = -1;
}

// ---------------------------------------------------------------------------
// K3: scatter packed records (coords, bin) into padded gene-sorted order.
// ---------------------------------------------------------------------------
__global__ __launch_bounds__(HTPB) void scatter_k(
    const int* __restrict__ gm, const float* __restrict__ coords,
    const int* __restrict__ lcg, int* __restrict__ cursor,
    float* __restrict__ xs, int* __restrict__ bins,
    int n_frag, int n_genes)
{
    __shared__ int lcnt[MAXG];
    __shared__ int lbase[MAXG];
    for (int t = threadIdx.x; t < MAXG; t += HTPB) lcnt[t] = 0;
    __syncthreads();

    int base = blockIdx.x * HCHUNK;
    int g[HFPT], lr[HFPT];
#pragma unroll
    for (int j = 0; j < HFPT; ++j) {
        int f = base + j * HTPB + (int)threadIdx.x;
        if (f < n_frag) {
            g[j]  = gm[f];
            lr[j] = atomicAdd(&lcnt[g[j]], 1);
        } else {
            g[j] = -1;
        }
    }
    __syncthreads();
    for (int t = threadIdx.x; t < MAXG; t += HTPB) {
        int c = lcnt[t];
        lbase[t] = c ? atomicAdd(&cursor[t], c) : 0;
    }
    __syncthreads();
#pragma unroll
    for (int j = 0; j < HFPT; ++j) {
        if (g[j] >= 0) {
            int f = base + j * HTPB + (int)threadIdx.x;
            int pos = lbase[g[j]] + lr[j];
            float2 xy = ((const float2*)coords)[f];
            xs[2 * pos + 0] = xy.x;
            xs[2 * pos + 1] = xy.y;
            bins[pos] = lcg[f];
        }
    }
}

// ---------------------------------------------------------------------------
// K4: main (MFMA) — each gene-uniform wave computes its 64 fragments' h via
// 4 M-tiles x 7 K-steps of mfma_f32_16x16x32_bf16. A (sine embedding) is
// generated in-register per lane; B (w1 row) preloaded once per wave as bf16.
// C/D layout (HW-verified): col = lane&15, row = (lane>>4)*4 + reg.
// A/B k-slot convention is self-consistent between A and B, so any bijective
// hardware k-permutation contracts correctly.
// ---------------------------------------------------------------------------
__global__ __launch_bounds__(256) void main_mfma_k(
    const float* __restrict__ w1, const float* __restrict__ b1,
    const float* __restrict__ w2, const int* __restrict__ genes_oi,
    const float* __restrict__ xs, const int* __restrict__ bins,
    const int* __restrict__ po, const int* __restrict__ cnt,
    const int* __restrict__ w2g, float* __restrict__ out,
    int gene_n, int wmax)
{
    __shared__ float fr[NF];
    if (threadIdx.x < NF) {
        float ex = (-2.0f * (float)(threadIdx.x + 1) / (float)NF) * 9.965784284662087f;
        fr[threadIdx.x] = exp2f(ex) * 0.15915494309189535f;  // base/(2*pi): revolutions
    }
    __syncthreads();

    int wid  = threadIdx.x >> 6;
    int lane = threadIdx.x & 63;
    int fw   = blockIdx.x * 4 + wid;          // frag-wave index

    int g = (fw < wmax) ? w2g[fw] : -1;
    g = __builtin_amdgcn_readfirstlane(g);
    if (g < 0) return;                        // wave-uniform exit, no barriers below

    int d  = lane & 15;                       // output dim / B col / A row offset
    int q  = lane >> 4;                       // k-group
    int dc = (d < 10) ? d : 9;                // clamped (in-bounds) dim

    int start = po[g];
    int count = cnt[g];
    int pos   = fw * 64 + lane;
    bool valid = (pos - start) < count;
    float2 xy = valid ? ((const float2*)xs)[pos] : make_float2(0.0f, 0.0f);

    // ---- B: preload gene's w1 row as 7 bf16x8 fragments (56 floats/lane) ----
    const float* wg = w1 + (size_t)g * W1G;
    short8v breg[7];
#pragma unroll
    for (int kk = 0; kk < 7; ++kk) {
#pragma unroll
        for (int j = 0; j < 8; ++j) {
            int k  = kk * 32 + q * 8 + j;
            int kc = (k < 200) ? k : 199;
            float v = wg[kc * 10 + dc];
            v = (k < 200 && d < 10) ? v : 0.0f;
            breg[kk][j] = f2bf(v);
        }
    }

    // ---- accumulators, initialized with b1 (same for every row) ----
    float b1v = b1[(size_t)g * DEMB + dc];
    f32x4v acc[4];
#pragma unroll
    for (int m = 0; m < 4; ++m) { acc[m][0] = b1v; acc[m][1] = b1v; acc[m][2] = b1v; acc[m][3] = b1v; }

    // ---- main MFMA loop: A generated in-register ----
#pragma unroll
    for (int m = 0; m < 4; ++m) {
        int srcA = m * 16 + d;                // fragment whose A-row this lane supplies
        float ax = __shfl(xy.x, srcA);
        float ay = __shfl(xy.y, srcA);
#pragma unroll
        for (int kk = 0; kk < 7; ++kk) {
            short8v afrag;
#pragma unroll
            for (int jj = 0; jj < 4; ++jj) {
                int k0 = kk * 32 + q * 8 + 2 * jj;   // even; (sin,cos) pair
                int cc = (k0 >= 100) ? 1 : 0;
                int ii = (k0 - cc * 100) >> 1;
                ii = (k0 < 200) ? ii : 0;            // clamp pad region
                float fv = fr[ii];
                float xv = cc ? ay : ax;
                float r = xv * fv; r -= rintf(r);    // revolutions in [-0.5,0.5]
                afrag[2 * jj]     = f2bf(__builtin_amdgcn_sinf(r));
                afrag[2 * jj + 1] = f2bf(__builtin_amdgcn_cosf(r));
            }
            acc[m] = __builtin_amdgcn_mfma_f32_16x16x32_bf16(afrag, breg[kk], acc[m], 0, 0, 0);
        }
    }

    // ---- epilogue: sigmoid, dot with w2 row, reduce over d, atomicAdd ----
    int bin_own  = valid ? bins[pos] : 0;
    int col_own  = (int)((unsigned)bin_own % (unsigned)gene_n);
    int gidx_own = valid ? genes_oi[col_own] : 0;
    int vown     = valid ? 1 : 0;

#pragma unroll
    for (int m = 0; m < 4; ++m) {
#pragma unroll
        for (int reg = 0; reg < 4; ++reg) {
            int src = m * 16 + q * 4 + reg;   // fragment this (m,reg) row belongs to
            int b   = __shfl(bin_own, src);
            int gi  = __shfl(gidx_own, src);
            int vf  = __shfl(vown, src);
            float hv = acc[m][reg];
            float w2v = w2[gi * DEMB + dc];
            float sg  = 1.0f / (1.0f + __expf(-hv));
            float s   = (d < 10) ? sg * w2v : 0.0f;
#pragma unroll
            for (int off = 1; off < 16; off <<= 1) s += __shfl_xor(s, off);
            if (d == 0 && vf) atomicAdd(&out[b], s);
        }
    }
}

// ---------------------------------------------------------------------------
// Fallback (workspace too small): one thread per fragment, non-uniform gene
// ---------------------------------------------------------------------------
__global__ __launch_bounds__(256) void frag_naive_k(
    const float* __restrict__ coords, const float* __restrict__ w1,
    const float* __restrict__ b1, const float* __restrict__ w2,
    const int* __restrict__ gm, const int* __restrict__ lcg,
    const int* __restrict__ genes_oi, float* __restrict__ out,
    int gene_n, int n_frag)
{
    __shared__ float fr[NF];
    if (threadIdx.x < NF) {
        float ex = (-2.0f * (float)(threadIdx.x + 1) / (float)NF) * 9.965784284662087f;
        fr[threadIdx.x] = exp2f(ex) * 0.15915494309189535f;
    }
    __syncthreads();

    int f = blockIdx.x * blockDim.x + threadIdx.x;
    if (f >= n_frag) return;
    int g = gm[f];
    const float* wrow  = w1 + (size_t)g * W1G;
    const float* b1row = b1 + (size_t)g * DEMB;
    float x0 = coords[2 * f + 0];
    float x1 = coords[2 * f + 1];

    float h[DEMB];
#pragma unroll
    for (int d = 0; d < DEMB; ++d) h[d] = b1row[d];
#pragma unroll 2
    for (int i = 0; i < NF; ++i) {
        float fv = fr[i];
        float r0 = x0 * fv; r0 -= rintf(r0);
        float r1 = x1 * fv; r1 -= rintf(r1);
        float s0 = __builtin_amdgcn_sinf(r0), c0 = __builtin_amdgcn_cosf(r0);
        float s1 = __builtin_amdgcn_sinf(r1), c1 = __builtin_amdgcn_cosf(r1);
        const float* wa = wrow + (2 * i) * DEMB;
        const float* wb = wrow + (2 * NF + 2 * i) * DEMB;
#pragma unroll
        for (int d = 0; d < DEMB; ++d) {
            h[d] += s0 * wa[d] + c0 * wa[DEMB + d] + s1 * wb[d] + c1 * wb[DEMB + d];
        }
    }
    int bin = lcg[f];
    int col = (int)((unsigned)bin % (unsigned)gene_n);
    const float* w2row = w2 + (size_t)genes_oi[col] * DEMB;
    float sum = 0.0f;
#pragma unroll
    for (int d = 0; d < DEMB; ++d) {
        float sg = 1.0f / (1.0f + __expf(-h[d]));
        sum += sg * w2row[d];
    }
    atomicAdd(&out[bin], sum);
}

__global__ void init_out_k(float* __restrict__ out, const float* __restrict__ b2,
                           const int* __restrict__ genes_oi, int gene_n, int total)
{
    int i = blockIdx.x * blockDim.x + threadIdx.x;
    if (i < total) {
        int col = (int)((unsigned)i % (unsigned)gene_n);
        out[i] = b2[genes_oi[col]];
    }
}

// ---------------------------------------------------------------------------
extern "C" void kernel_launch(void* const* d_in, const int* in_sizes, int n_in,
                              void* d_out, int out_size, void* d_ws, size_t ws_size,
                              hipStream_t stream)
{
    const float* coords   = (const float*)d_in[0];
    const float* w1       = (const float*)d_in[1];
    const float* b1       = (const float*)d_in[2];
    const float* w2       = (const float*)d_in[3];
    const float* b2       = (const float*)d_in[4];
    const int*   gm       = (const int*)d_in[5];
    const int*   lcg      = (const int*)d_in[6];
    const int*   genes_oi = (const int*)d_in[7];

    int n_frag  = in_sizes[5];
    int n_genes = in_sizes[4];
    int gene_n  = in_sizes[7];
    int total   = out_size;
    float* out  = (float*)d_out;

    int nblk = (n_frag + HCHUNK - 1) / HCHUNK;
    int wmax = (n_frag >> 6) + n_genes + 1;            // upper bound on frag-waves
    size_t padcap = (size_t)n_frag + 64 * (size_t)n_genes + 64;

    // workspace layout
    int* counts_mat = (int*)d_ws;                          // [nblk][MAXG]
    int* po         = counts_mat + (size_t)nblk * MAXG;    // [MAXG+1]
    int* cursor     = po + (MAXG + 1);                     // [MAXG]
    int* cnt        = cursor + MAXG;                       // [MAXG]
    int* w2g        = cnt + MAXG;                          // [wmax]
    float* xs       = (float*)(w2g + wmax);                // [2*padcap]
    int* bins       = (int*)(xs + 2 * padcap);             // [padcap]
    size_t need = ((size_t)nblk * MAXG + (MAXG + 1) + 2 * MAXG + wmax
                   + 3 * padcap) * sizeof(int);

    bool use_sorted = (ws_size >= need) && (n_genes <= MAXG);
    if (use_sorted) {
        hist_init_k<<<nblk, HTPB, 0, stream>>>(gm, n_frag, n_genes, counts_mat,
                                               out, b2, genes_oi, gene_n, total);
        scan_k<<<1, MAXG, 0, stream>>>(counts_mat, nblk, po, cursor, cnt, w2g,
                                       n_genes, wmax);
        scatter_k<<<nblk, HTPB, 0, stream>>>(gm, coords, lcg, cursor,
                                             xs, bins, n_frag, n_genes);
        int mblk = (wmax + 3) / 4;
        main_mfma_k<<<mblk, 256, 0, stream>>>(w1, b1, w2, genes_oi, xs, bins,
                                              po, cnt, w2g, out, gene_n, wmax);
    } else {
        init_out_k<<<(total + 255) / 256, 256, 0, stream>>>(out, b2, genes_oi, gene_n, total);
        frag_naive_k<<<(n_frag + 255) / 256, 256, 0, stream>>>(coords, w1, b1, w2, gm, lcg,
                                                               genes_oi, out, gene_n, n_frag);
    }
}

// Round 8
// 49.886 us; speedup vs baseline: 1.6942x; 1.0358x over previous
//
#include <hip/hip_runtime.h>
#include <hip/hip_bf16.h>
#include <math.h>

#define NF    50              // n_frequencies
#define DEMB  10              // embedding dim
#define W1G   (4 * NF * DEMB) // 2000 floats of w1 per gene
#define MAXG  512             // max genes supported by sort path

#define HTPB   256
#define HCHUNK 4096
#define HFPT   (HCHUNK / HTPB) // 16 fragments per thread in hist/scatter

#define KPAD  232             // bf16 k-stride of LDS B tile (464 B rows)
#define HPAD  19              // fp32 stride of LDS h tile
#define W2PAD 11              // fp32 stride of LDS w2 tile
#define ARENA 7680            // per-wave LDS arena bytes (B tile / h tile alias)

typedef __attribute__((ext_vector_type(8))) short short8v;  // 8 bf16
typedef __attribute__((ext_vector_type(4))) float f32x4v;

__device__ __forceinline__ short f2bf(float f) {
    unsigned u = __float_as_uint(f);
    u += 0x7fffu + ((u >> 16) & 1u);    // RNE
    return (short)(u >> 16);
}

// ---------------------------------------------------------------------------
// K1: per-block private histogram rows (no global atomics) + out init with b2
// ---------------------------------------------------------------------------
__global__ __launch_bounds__(HTPB) void hist_init_k(
    const int* __restrict__ gm, int n_frag, int n_genes,
    int* __restrict__ counts_mat,                 // [gridDim.x][MAXG]
    float* __restrict__ out, const float* __restrict__ b2,
    const int* __restrict__ genes_oi, int gene_n, int total)
{
    __shared__ int lcnt[MAXG];
    for (int t = threadIdx.x; t < MAXG; t += HTPB) lcnt[t] = 0;
    __syncthreads();

    int base = blockIdx.x * HCHUNK;
#pragma unroll
    for (int j = 0; j < HFPT; ++j) {
        int f = base + j * HTPB + (int)threadIdx.x;
        if (f < n_frag) atomicAdd(&lcnt[gm[f]], 1);
    }

    int nthreads = gridDim.x * HTPB;
    for (int i = blockIdx.x * HTPB + (int)threadIdx.x; i < total; i += nthreads) {
        int col = (int)((unsigned)i % (unsigned)gene_n);
        out[i] = b2[genes_oi[col]];
    }

    __syncthreads();
    int* row = counts_mat + (size_t)blockIdx.x * MAXG;
    for (int t = threadIdx.x; t < MAXG; t += HTPB) row[t] = lcnt[t];
}

// ---------------------------------------------------------------------------
// K2: reduce count matrix; scan of 64-PADDED counts; build wave->gene table.
// ---------------------------------------------------------------------------
__global__ void scan_k(const int* __restrict__ counts_mat, int nblk,
                       int* __restrict__ po, int* __restrict__ cursor,
                       int* __restrict__ cnt, int* __restrict__ w2g,
                       int n_genes, int wmax)
{
    __shared__ int buf[MAXG];
    int tid = threadIdx.x;
    int s = 0;
#pragma unroll 8
    for (int b = 0; b < nblk; ++b) s += counts_mat[(size_t)b * MAXG + tid];
    int pc = ((s + 63) >> 6) << 6;       // padded count
    buf[tid] = pc;
    __syncthreads();
    for (int d = 1; d < MAXG; d <<= 1) {
        int t = (tid >= d) ? buf[tid - d] : 0;
        __syncthreads();
        buf[tid] += t;
        __syncthreads();
    }
    int incl = buf[tid];
    if (tid < n_genes) {
        po[tid + 1] = incl;
        cursor[tid] = incl - pc;
        cnt[tid]    = s;
        int wbeg = (incl - pc) >> 6;
        int wend = incl >> 6;
        for (int w = wbeg; w < wend; ++w) w2g[w] = tid;
    }
    if (tid == 0) po[0] = 0;
    __syncthreads();
    int W = buf[n_genes - 1] >> 6;
    for (int w = W + tid; w < wmax; w += MAXG) w2g[w] = -1;
}

// ---------------------------------------------------------------------------
// K3: scatter packed records (coords, bin) into padded gene-sorted order.
// ---------------------------------------------------------------------------
__global__ __launch_bounds__(HTPB) void scatter_k(
    const int* __restrict__ gm, const float* __restrict__ coords,
    const int* __restrict__ lcg, int* __restrict__ cursor,
    float* __restrict__ xs, int* __restrict__ bins,
    int n_frag, int n_genes)
{
    __shared__ int lcnt[MAXG];
    __shared__ int lbase[MAXG];
    for (int t = threadIdx.x; t < MAXG; t += HTPB) lcnt[t] = 0;
    __syncthreads();

    int base = blockIdx.x * HCHUNK;
    int g[HFPT], lr[HFPT];
#pragma unroll
    for (int j = 0; j < HFPT; ++j) {
        int f = base + j * HTPB + (int)threadIdx.x;
        if (f < n_frag) {
            g[j]  = gm[f];
            lr[j] = atomicAdd(&lcnt[g[j]], 1);
        } else {
            g[j] = -1;
        }
    }
    __syncthreads();
    for (int t = threadIdx.x; t < MAXG; t += HTPB) {
        int c = lcnt[t];
        lbase[t] = c ? atomicAdd(&cursor[t], c) : 0;
    }
    __syncthreads();
#pragma unroll
    for (int j = 0; j < HFPT; ++j) {
        if (g[j] >= 0) {
            int f = base + j * HTPB + (int)threadIdx.x;
            int pos = lbase[g[j]] + lr[j];
            float2 xy = ((const float2*)coords)[f];
            xs[2 * pos + 0] = xy.x;
            xs[2 * pos + 1] = xy.y;
            bins[pos] = lcg[f];
        }
    }
}

// ---------------------------------------------------------------------------
// K4: main (MFMA v2).
//  - B: wave loads its gene's w1 row COALESCED, bf16-converts into a per-wave
//    LDS tile [d][KPAD], then 7 x ds_read_b128 give all B fragments.
//  - A: sine embedding generated in-register (as r7, HW-verified passing).
//  - Epilogue: acc -> LDS h tile [frag][HPAD]; each lane then owns its own
//    fragment: 10 ds_read + sigmoid + dot with LDS-staged w2 + 1 atomicAdd.
//  - h tile aliases the B tile (per-wave arena; wave-internal DS ordering).
// ---------------------------------------------------------------------------
__global__ __launch_bounds__(256) void main_mfma_k(
    const float* __restrict__ w1, const float* __restrict__ b1,
    const float* __restrict__ w2, const int* __restrict__ genes_oi,
    const float* __restrict__ xs, const int* __restrict__ bins,
    const int* __restrict__ po, const int* __restrict__ cnt,
    const int* __restrict__ w2g, float* __restrict__ out,
    int gene_n, int wmax)
{
    __shared__ float fr[NF];
    __shared__ float w2l[MAXG * W2PAD];
    __shared__ __align__(16) char arena[4][ARENA];

    if (threadIdx.x < NF) {
        float ex = (-2.0f * (float)(threadIdx.x + 1) / (float)NF) * 9.965784284662087f;
        fr[threadIdx.x] = exp2f(ex) * 0.15915494309189535f;  // base/(2*pi): revolutions
    }
    // stage w2 (already indexed through genes_oi) into LDS
    for (int c = threadIdx.x; c < gene_n; c += 256) {
        int gi = genes_oi[c];
#pragma unroll
        for (int dd = 0; dd < DEMB; ++dd)
            w2l[c * W2PAD + dd] = w2[(size_t)gi * DEMB + dd];
    }
    __syncthreads();

    int wid  = threadIdx.x >> 6;
    int lane = threadIdx.x & 63;
    int fw   = blockIdx.x * 4 + wid;          // frag-wave index

    int g = (fw < wmax) ? w2g[fw] : -1;
    g = __builtin_amdgcn_readfirstlane(g);
    if (g < 0) return;                        // after the only barrier

    int d  = lane & 15;                       // output dim / B col
    int q  = lane >> 4;                       // k-group
    int dc = (d < 10) ? d : 9;                // clamped dim

    int start = po[g];
    int count = cnt[g];
    int pos   = fw * 64 + lane;
    bool valid = (pos - start) < count;
    float2 xy = valid ? ((const float2*)xs)[pos] : make_float2(0.0f, 0.0f);
    int bin_own = valid ? bins[pos] : 0;
    int col_own = (int)((unsigned)bin_own % (unsigned)gene_n);

    // ---- stage B: coalesced load of w1 row -> bf16 LDS tile [d][KPAD] ----
    short* Bw = (short*)(arena[wid]);
    const float* wg = w1 + (size_t)g * W1G;
#pragma unroll
    for (int r = 0; r < 8; ++r) {
        int e4 = r * 64 + lane;
        if (e4 < W1G / 4) {
            float4 v = ((const float4*)wg)[e4];
            int e = e4 * 4;
            int k0 = e / 10, d0 = e - k0 * 10;
#pragma unroll
            for (int c = 0; c < 4; ++c) {
                Bw[d0 * KPAD + k0] = f2bf((&v.x)[c]);
                d0++; if (d0 == 10) { d0 = 0; k0++; }
            }
        }
    }
    // zero the k in [200, 224) tail so junk doesn't contract into real dims
    for (int idx = lane; idx < 320; idx += 64) {
        int row = idx >> 5, kz = 200 + (idx & 31);
        Bw[row * KPAD + kz] = 0;
    }

    // ---- read B fragments: 7 x ds_read_b128 ----
    short8v breg[7];
    {
        const char* bp = arena[wid] + dc * (KPAD * 2) + q * 16;
#pragma unroll
        for (int kk = 0; kk < 7; ++kk)
            breg[kk] = *(const short8v*)(bp + kk * 64);
    }

    // ---- accumulators init with b1 ----
    float b1v = b1[(size_t)g * DEMB + dc];
    f32x4v acc[4];
#pragma unroll
    for (int m = 0; m < 4; ++m) { acc[m][0] = b1v; acc[m][1] = b1v; acc[m][2] = b1v; acc[m][3] = b1v; }

    // ---- MFMA loop: A generated in-register (layout convention as r7) ----
#pragma unroll
    for (int m = 0; m < 4; ++m) {
        int srcA = m * 16 + d;
        float ax = __shfl(xy.x, srcA);
        float ay = __shfl(xy.y, srcA);
#pragma unroll
        for (int kk = 0; kk < 7; ++kk) {
            short8v afrag;
#pragma unroll
            for (int jj = 0; jj < 4; ++jj) {
                int k0 = kk * 32 + q * 8 + 2 * jj;   // (sin,cos) pair at even k
                int cc = (k0 >= 100) ? 1 : 0;
                int ii = (k0 - cc * 100) >> 1;
                ii = (k0 < 200) ? ii : 0;            // pad region: B is zero there
                float fv = fr[ii];
                float xv = cc ? ay : ax;
                float r = xv * fv; r -= rintf(r);    // revolutions in [-0.5,0.5]
                afrag[2 * jj]     = f2bf(__builtin_amdgcn_sinf(r));
                afrag[2 * jj + 1] = f2bf(__builtin_amdgcn_cosf(r));
            }
            acc[m] = __builtin_amdgcn_mfma_f32_16x16x32_bf16(afrag, breg[kk], acc[m], 0, 0, 0);
        }
    }

    // ---- epilogue: transpose h via LDS (aliases B tile), lane owns fragment ----
    float* hb = (float*)(arena[wid]);
#pragma unroll
    for (int m = 0; m < 4; ++m)
#pragma unroll
        for (int r = 0; r < 4; ++r)
            hb[(m * 16 + q * 4 + r) * HPAD + d] = acc[m][r];

    float sum = 0.0f;
    const float* wrow2 = &w2l[col_own * W2PAD];
#pragma unroll
    for (int dd = 0; dd < DEMB; ++dd) {
        float hv = hb[lane * HPAD + dd];
        float sg = 1.0f / (1.0f + __expf(-hv));
        sum += sg * wrow2[dd];
    }
    if (valid) atomicAdd(&out[bin_own], sum);
}

// ---------------------------------------------------------------------------
// Fallback (workspace too small): one thread per fragment, non-uniform gene
// ---------------------------------------------------------------------------
__global__ __launch_bounds__(256) void frag_naive_k(
    const float* __restrict__ coords, const float* __restrict__ w1,
    const float* __restrict__ b1, const float* __restrict__ w2,
    const int* __restrict__ gm, const int* __restrict__ lcg,
    const int* __restrict__ genes_oi, float* __restrict__ out,
    int gene_n, int n_frag)
{
    __shared__ float fr[NF];
    if (threadIdx.x < NF) {
        float ex = (-2.0f * (float)(threadIdx.x + 1) / (float)NF) * 9.965784284662087f;
        fr[threadIdx.x] = exp2f(ex) * 0.15915494309189535f;
    }
    __syncthreads();

    int f = blockIdx.x * blockDim.x + threadIdx.x;
    if (f >= n_frag) return;
    int g = gm[f];
    const float* wrow  = w1 + (size_t)g * W1G;
    const float* b1row = b1 + (size_t)g * DEMB;
    float x0 = coords[2 * f + 0];
    float x1 = coords[2 * f + 1];

    float h[DEMB];
#pragma unroll
    for (int d = 0; d < DEMB; ++d) h[d] = b1row[d];
#pragma unroll 2
    for (int i = 0; i < NF; ++i) {
        float fv = fr[i];
        float r0 = x0 * fv; r0 -= rintf(r0);
        float r1 = x1 * fv; r1 -= rintf(r1);
        float s0 = __builtin_amdgcn_sinf(r0), c0 = __builtin_amdgcn_cosf(r0);
        float s1 = __builtin_amdgcn_sinf(r1), c1 = __builtin_amdgcn_cosf(r1);
        const float* wa = wrow + (2 * i) * DEMB;
        const float* wb = wrow + (2 * NF + 2 * i) * DEMB;
#pragma unroll
        for (int d = 0; d < DEMB; ++d) {
            h[d] += s0 * wa[d] + c0 * wa[DEMB + d] + s1 * wb[d] + c1 * wb[DEMB + d];
        }
    }
    int bin = lcg[f];
    int col = (int)((unsigned)bin % (unsigned)gene_n);
    const float* w2row = w2 + (size_t)genes_oi[col] * DEMB;
    float sum = 0.0f;
#pragma unroll
    for (int d = 0; d < DEMB; ++d) {
        float sg = 1.0f / (1.0f + __expf(-h[d]));
        sum += sg * w2row[d];
    }
    atomicAdd(&out[bin], sum);
}

__global__ void init_out_k(float* __restrict__ out, const float* __restrict__ b2,
                           const int* __restrict__ genes_oi, int gene_n, int total)
{
    int i = blockIdx.x * blockDim.x + threadIdx.x;
    if (i < total) {
        int col = (int)((unsigned)i % (unsigned)gene_n);
        out[i] = b2[genes_oi[col]];
    }
}

// ---------------------------------------------------------------------------
extern "C" void kernel_launch(void* const* d_in, const int* in_sizes, int n_in,
                              void* d_out, int out_size, void* d_ws, size_t ws_size,
                              hipStream_t stream)
{
    const float* coords   = (const float*)d_in[0];
    const float* w1       = (const float*)d_in[1];
    const float* b1       = (const float*)d_in[2];
    const float* w2       = (const float*)d_in[3];
    const float* b2       = (const float*)d_in[4];
    const int*   gm       = (const int*)d_in[5];
    const int*   lcg      = (const int*)d_in[6];
    const int*   genes_oi = (const int*)d_in[7];

    int n_frag  = in_sizes[5];
    int n_genes = in_sizes[4];
    int gene_n  = in_sizes[7];
    int total   = out_size;
    float* out  = (float*)d_out;

    int nblk = (n_frag + HCHUNK - 1) / HCHUNK;
    int wmax = (n_frag >> 6) + n_genes + 1;            // upper bound on frag-waves
    size_t padcap = (size_t)n_frag + 64 * (size_t)n_genes + 64;

    // workspace layout
    int* counts_mat = (int*)d_ws;                          // [nblk][MAXG]
    int* po         = counts_mat + (size_t)nblk * MAXG;    // [MAXG+1]
    int* cursor     = po + (MAXG + 1);                     // [MAXG]
    int* cnt        = cursor + MAXG;                       // [MAXG]
    int* w2g        = cnt + MAXG;                          // [wmax]
    float* xs       = (float*)(w2g + wmax);                // [2*padcap]
    int* bins       = (int*)(xs + 2 * padcap);             // [padcap]
    size_t need = ((size_t)nblk * MAXG + (MAXG + 1) + 2 * MAXG + wmax
                   + 3 * padcap) * sizeof(int);

    bool use_sorted = (ws_size >= need) && (n_genes <= MAXG);
    if (use_sorted) {
        hist_init_k<<<nblk, HTPB, 0, stream>>>(gm, n_frag, n_genes, counts_mat,
                                               out, b2, genes_oi, gene_n, total);
        scan_k<<<1, MAXG, 0, stream>>>(counts_mat, nblk, po, cursor, cnt, w2g,
                                       n_genes, wmax);
        scatter_k<<<nblk, HTPB, 0, stream>>>(gm, coords, lcg, cursor,
                                             xs, bins, n_frag, n_genes);
        int mblk = (wmax + 3) / 4;
        main_mfma_k<<<mblk, 256, 0, stream>>>(w1, b1, w2, genes_oi, xs, bins,
                                              po, cnt, w2g, out, gene_n, wmax);
    } else {
        init_out_k<<<(total + 255) / 256, 256, 0, stream>>>(out, b2, genes_oi, gene_n, total);
        frag_naive_k<<<(n_frag + 255) / 256, 256, 0, stream>>>(coords, w1, b1, w2, gm, lcg,
                                                               genes_oi, out, gene_n, n_frag);
    }
}

// Round 10
// 46.008 us; speedup vs baseline: 1.8370x; 1.0843x over previous
//
#include <hip/hip_runtime.h>
#include <hip/hip_bf16.h>
#include <math.h>

#define NF    50              // n_frequencies
#define DEMB  10              // embedding dim
#define W1G   (4 * NF * DEMB) // 2000 floats of w1 per gene
#define MAXG  512             // max genes supported by sort path

#define HTPB   256
#define HCHUNK 4096
#define HFPT   (HCHUNK / HTPB) // 16 fragments per thread in hist/scatter

#define HPAD  11              // fp32 stride of per-wave LDS h tile
#define TKP   208             // transpose tile k-stride (bf16)

typedef __attribute__((ext_vector_type(8))) short short8v;      // 8 bf16
typedef __attribute__((ext_vector_type(4))) unsigned int uint4v;
typedef __attribute__((ext_vector_type(4))) float f32x4v;

__device__ __forceinline__ short f2bf(float f) {
    union { __hip_bfloat16 b; unsigned short u; } v;
    v.b = __float2bfloat16(f);
    return (short)v.u;
}
__device__ __forceinline__ unsigned pkbf(float lo, float hi) {
    union { __hip_bfloat162 b; unsigned u; } v;
    v.b = __float22bfloat162_rn(make_float2(lo, hi));   // .x -> low half
    return v.u;
}

// ---------------------------------------------------------------------------
// K1: per-block private histogram rows + out init with b2 + w1 transpose.
// grid = max(nblk, n_genes). Blocks < nblk do the histogram chunk; blocks
// < n_genes transpose their gene's w1 row into bf16 w1T[g][d][k] (coalesced
// read, LDS transpose, coalesced 16B writes).
// ---------------------------------------------------------------------------
__global__ __launch_bounds__(HTPB) void hist_init_k(
    const int* __restrict__ gm, const float* __restrict__ w1,
    short* __restrict__ w1T, int n_frag, int n_genes, int nblk,
    int* __restrict__ counts_mat,                 // [nblk][MAXG]
    float* __restrict__ out, const float* __restrict__ b2,
    const int* __restrict__ genes_oi, int gene_n, int total)
{
    __shared__ int lcnt[MAXG];
    __shared__ __align__(16) short tile[DEMB][TKP];

    bool do_hist = (int)blockIdx.x < nblk;
    bool do_tr   = (int)blockIdx.x < n_genes;

    for (int t = threadIdx.x; t < MAXG; t += HTPB) lcnt[t] = 0;
    __syncthreads();

    if (do_hist) {
        int base = blockIdx.x * HCHUNK;
#pragma unroll
        for (int j = 0; j < HFPT; ++j) {
            int f = base + j * HTPB + (int)threadIdx.x;
            if (f < n_frag) atomicAdd(&lcnt[gm[f]], 1);
        }
    }

    if (do_tr) {
        const float* wg = w1 + (size_t)blockIdx.x * W1G;
        for (int e4 = threadIdx.x; e4 < W1G / 4; e4 += HTPB) {
            float4 v = ((const float4*)wg)[e4];
            int e = e4 * 4;
            int k0 = e / 10, d0 = e - k0 * 10;
#pragma unroll
            for (int c = 0; c < 4; ++c) {
                tile[d0][k0] = f2bf((&v.x)[c]);
                d0++; if (d0 == 10) { d0 = 0; k0++; }
            }
        }
    }

    // init out with broadcast b2 (grid-stride)
    int nthreads = gridDim.x * HTPB;
    for (int i = blockIdx.x * HTPB + (int)threadIdx.x; i < total; i += nthreads) {
        int col = (int)((unsigned)i % (unsigned)gene_n);
        out[i] = b2[genes_oi[col]];
    }
    // zero the small tail after w1T (over-read by kk=6 B loads; A=0 there,
    // but keep the bytes finite/defined)
    if (blockIdx.x == 0 && threadIdx.x < 64)
        w1T[(size_t)n_genes * 2000 + threadIdx.x] = 0;

    __syncthreads();

    if (do_hist) {
        int* row = counts_mat + (size_t)blockIdx.x * MAXG;
        for (int t = threadIdx.x; t < MAXG; t += HTPB) row[t] = lcnt[t];
    }
    if (do_tr) {
        short* og = w1T + (size_t)blockIdx.x * 2000;
        for (int o = threadIdx.x; o < 250; o += HTPB) {
            int dd = o / 25;
            int off = (o - dd * 25) * 8;
            *(short8v*)(og + dd * 200 + off) = *(const short8v*)&tile[dd][off];
        }
    }
}

// ---------------------------------------------------------------------------
// K2: reduce count matrix; scan of 64-PADDED counts; build wave->gene table.
// ---------------------------------------------------------------------------
__global__ void scan_k(const int* __restrict__ counts_mat, int nblk,
                       int* __restrict__ po, int* __restrict__ cursor,
                       int* __restrict__ cnt, int* __restrict__ w2g,
                       int n_genes, int wmax)
{
    __shared__ int buf[MAXG];
    int tid = threadIdx.x;
    int s = 0;
#pragma unroll 8
    for (int b = 0; b < nblk; ++b) s += counts_mat[(size_t)b * MAXG + tid];
    int pc = ((s + 63) >> 6) << 6;       // padded count
    buf[tid] = pc;
    __syncthreads();
    for (int d = 1; d < MAXG; d <<= 1) {
        int t = (tid >= d) ? buf[tid - d] : 0;
        __syncthreads();
        buf[tid] += t;
        __syncthreads();
    }
    int incl = buf[tid];
    if (tid < n_genes) {
        po[tid + 1] = incl;
        cursor[tid] = incl - pc;
        cnt[tid]    = s;
        int wbeg = (incl - pc) >> 6;
        int wend = incl >> 6;
        for (int w = wbeg; w < wend; ++w) w2g[w] = tid;
    }
    if (tid == 0) po[0] = 0;
    __syncthreads();
    int W = buf[n_genes - 1] >> 6;
    for (int w = W + tid; w < wmax; w += MAXG) w2g[w] = -1;
}

// ---------------------------------------------------------------------------
// K3: scatter packed records (coords, bin) into padded gene-sorted order.
// ---------------------------------------------------------------------------
__global__ __launch_bounds__(HTPB) void scatter_k(
    const int* __restrict__ gm, const float* __restrict__ coords,
    const int* __restrict__ lcg, int* __restrict__ cursor,
    float* __restrict__ xs, int* __restrict__ bins,
    int n_frag, int n_genes)
{
    __shared__ int lcnt[MAXG];
    __shared__ int lbase[MAXG];
    for (int t = threadIdx.x; t < MAXG; t += HTPB) lcnt[t] = 0;
    __syncthreads();

    int base = blockIdx.x * HCHUNK;
    int g[HFPT], lr[HFPT];
#pragma unroll
    for (int j = 0; j < HFPT; ++j) {
        int f = base + j * HTPB + (int)threadIdx.x;
        if (f < n_frag) {
            g[j]  = gm[f];
            lr[j] = atomicAdd(&lcnt[g[j]], 1);
        } else {
            g[j] = -1;
        }
    }
    __syncthreads();
    for (int t = threadIdx.x; t < MAXG; t += HTPB) {
        int c = lcnt[t];
        lbase[t] = c ? atomicAdd(&cursor[t], c) : 0;
    }
    __syncthreads();
#pragma unroll
    for (int j = 0; j < HFPT; ++j) {
        if (g[j] >= 0) {
            int f = base + j * HTPB + (int)threadIdx.x;
            int pos = lbase[g[j]] + lr[j];
            float2 xy = ((const float2*)coords)[f];
            xs[2 * pos + 0] = xy.x;
            xs[2 * pos + 1] = xy.y;
            bins[pos] = lcg[f];
        }
    }
}

// ---------------------------------------------------------------------------
// K4: main (MFMA v3) — minimal LDS (~12KB), high occupancy.
//  - B: 7 direct 16B loads/lane from bf16 w1T[g][d][k] (L1-hot, shared by
//    the ~7 waves of each gene).
//  - A: sine embedding generated in-register; freq operands preloaded into
//    28 registers (7 ds_read_b128, reused across all 4 M-tiles).
//  - k>=200 pad: A forced to 0 (B bytes there are defined-finite).
//  - Epilogue: per-wave LDS h-transpose (write GUARDED to d<10 — with
//    HPAD=11 < 16, junk-column writes would stomp the next row: r9 bug),
//    then each lane owns its fragment: 10 ds_read + sigmoid + dot(w2) +
//    1 atomicAdd.
// ---------------------------------------------------------------------------
__global__ __launch_bounds__(256, 4) void main_mfma_k(
    const short* __restrict__ w1T, const float* __restrict__ b1,
    const float* __restrict__ w2, const int* __restrict__ genes_oi,
    const float* __restrict__ xs, const int* __restrict__ bins,
    const int* __restrict__ po, const int* __restrict__ cnt,
    const int* __restrict__ w2g, float* __restrict__ out,
    int gene_n, int wmax)
{
    __shared__ __align__(16) float fr_ext[116];     // fr[i mod 50]
    __shared__ __align__(16) float hb_all[4][64 * HPAD];

    if (threadIdx.x < 116) {
        int i = threadIdx.x;
        int im = (i < 50) ? i : ((i < 100) ? i - 50 : i - 100);
        float ex = (-2.0f * (float)(im + 1) / (float)NF) * 9.965784284662087f; // log2(1000)
        fr_ext[i] = exp2f(ex) * 0.15915494309189535f;   // base/(2*pi): revolutions
    }
    __syncthreads();

    int wid  = threadIdx.x >> 6;
    int lane = threadIdx.x & 63;
    int fw   = blockIdx.x * 4 + wid;          // frag-wave index

    int g = (fw < wmax) ? w2g[fw] : -1;
    g = __builtin_amdgcn_readfirstlane(g);
    if (g < 0) return;                        // after the only barrier

    int d  = lane & 15;                       // output dim / B col
    int q  = lane >> 4;                       // k-group
    int dc = (d < 10) ? d : 9;                // clamped dim (cols 10-15 unused junk)

    int start = po[g];
    int count = cnt[g];
    int pos   = fw * 64 + lane;
    bool valid = (pos - start) < count;
    float2 xy = valid ? ((const float2*)xs)[pos] : make_float2(0.0f, 0.0f);
    int bin_own = valid ? bins[pos] : 0;
    int col_own = (int)((unsigned)bin_own % (unsigned)gene_n);

    // ---- B fragments: 7 direct 16B loads from transposed w1T ----
    const short* bp = w1T + (size_t)g * 2000 + dc * 200 + q * 8;
    short8v breg[7];
#pragma unroll
    for (int kk = 0; kk < 7; ++kk)
        breg[kk] = *(const short8v*)(bp + kk * 32);

    // ---- freq operands into registers (reused across 4 M-tiles) ----
    float4 frv[7];
#pragma unroll
    for (int kk = 0; kk < 7; ++kk)
        frv[kk] = *(const float4*)&fr_ext[16 * kk + 4 * q];

    // ---- accumulators init with b1 ----
    float b1v = b1[(size_t)g * DEMB + dc];
    f32x4v acc[4];
#pragma unroll
    for (int m = 0; m < 4; ++m) { acc[m][0] = b1v; acc[m][1] = b1v; acc[m][2] = b1v; acc[m][3] = b1v; }

    // ---- MFMA loop: A generated in-register ----
#pragma unroll
    for (int m = 0; m < 4; ++m) {
        int srcA = m * 16 + d;                // fragment whose A-row this lane supplies
        float ax = __shfl(xy.x, srcA);
        float ay = __shfl(xy.y, srcA);
#pragma unroll
        for (int kk = 0; kk < 7; ++kk) {
            uint4v au;
#pragma unroll
            for (int jj = 0; jj < 4; ++jj) {
                int idx = 16 * kk + 4 * q + jj;        // = (k mod 200)/2 ; <50 -> coord0
                float fv = (&frv[kk].x)[jj];
                float xv = (idx < 50) ? ax : ay;
                float r = xv * fv; r -= rintf(r);      // revolutions in [-0.5,0.5]
                float sv = __builtin_amdgcn_sinf(r);
                float cv = __builtin_amdgcn_cosf(r);
                if (kk == 6) {                          // k>=200 pad: zero A
                    bool pad = (idx >= 100);
                    sv = pad ? 0.0f : sv;
                    cv = pad ? 0.0f : cv;
                }
                au[jj] = pkbf(sv, cv);                 // (sin, cos) -> 2 bf16
            }
            short8v afrag = __builtin_bit_cast(short8v, au);
            acc[m] = __builtin_amdgcn_mfma_f32_16x16x32_bf16(afrag, breg[kk], acc[m], 0, 0, 0);
        }
    }

    // ---- epilogue: per-wave LDS h-transpose; lane owns its fragment ----
    float* hb = hb_all[wid];
    if (d < 10) {                              // GUARD: junk cols must not write
#pragma unroll
        for (int m = 0; m < 4; ++m)
#pragma unroll
            for (int r = 0; r < 4; ++r)
                hb[(m * 16 + q * 4 + r) * HPAD + d] = acc[m][r];
    }

    int gi = genes_oi[col_own];
    const float* w2r = w2 + (size_t)gi * DEMB;
    float sum = 0.0f;
#pragma unroll
    for (int p2 = 0; p2 < 5; ++p2) {
        float2 wv = *(const float2*)(w2r + 2 * p2);
        float h0 = hb[lane * HPAD + 2 * p2];
        float h1 = hb[lane * HPAD + 2 * p2 + 1];
        sum += wv.x / (1.0f + __expf(-h0));
        sum += wv.y / (1.0f + __expf(-h1));
    }
    if (valid) atomicAdd(&out[bin_own], sum);
}

// ---------------------------------------------------------------------------
// Fallback (workspace too small): one thread per fragment, non-uniform gene
// ---------------------------------------------------------------------------
__global__ __launch_bounds__(256) void frag_naive_k(
    const float* __restrict__ coords, const float* __restrict__ w1,
    const float* __restrict__ b1, const float* __restrict__ w2,
    const int* __restrict__ gm, const int* __restrict__ lcg,
    const int* __restrict__ genes_oi, float* __restrict__ out,
    int gene_n, int n_frag)
{
    __shared__ float fr[NF];
    if (threadIdx.x < NF) {
        float ex = (-2.0f * (float)(threadIdx.x + 1) / (float)NF) * 9.965784284662087f;
        fr[threadIdx.x] = exp2f(ex) * 0.15915494309189535f;
    }
    __syncthreads();

    int f = blockIdx.x * blockDim.x + threadIdx.x;
    if (f >= n_frag) return;
    int g = gm[f];
    const float* wrow  = w1 + (size_t)g * W1G;
    const float* b1row = b1 + (size_t)g * DEMB;
    float x0 = coords[2 * f + 0];
    float x1 = coords[2 * f + 1];

    float h[DEMB];
#pragma unroll
    for (int d = 0; d < DEMB; ++d) h[d] = b1row[d];
#pragma unroll 2
    for (int i = 0; i < NF; ++i) {
        float fv = fr[i];
        float r0 = x0 * fv; r0 -= rintf(r0);
        float r1 = x1 * fv; r1 -= rintf(r1);
        float s0 = __builtin_amdgcn_sinf(r0), c0 = __builtin_amdgcn_cosf(r0);
        float s1 = __builtin_amdgcn_sinf(r1), c1 = __builtin_amdgcn_cosf(r1);
        const float* wa = wrow + (2 * i) * DEMB;
        const float* wb = wrow + (2 * NF + 2 * i) * DEMB;
#pragma unroll
        for (int d = 0; d < DEMB; ++d) {
            h[d] += s0 * wa[d] + c0 * wa[DEMB + d] + s1 * wb[d] + c1 * wb[DEMB + d];
        }
    }
    int bin = lcg[f];
    int col = (int)((unsigned)bin % (unsigned)gene_n);
    const float* w2row = w2 + (size_t)genes_oi[col] * DEMB;
    float sum = 0.0f;
#pragma unroll
    for (int d = 0; d < DEMB; ++d) {
        float sg = 1.0f / (1.0f + __expf(-h[d]));
        sum += sg * w2row[d];
    }
    atomicAdd(&out[bin], sum);
}

__global__ void init_out_k(float* __restrict__ out, const float* __restrict__ b2,
                           const int* __restrict__ genes_oi, int gene_n, int total)
{
    int i = blockIdx.x * blockDim.x + threadIdx.x;
    if (i < total) {
        int col = (int)((unsigned)i % (unsigned)gene_n);
        out[i] = b2[genes_oi[col]];
    }
}

// ---------------------------------------------------------------------------
extern "C" void kernel_launch(void* const* d_in, const int* in_sizes, int n_in,
                              void* d_out, int out_size, void* d_ws, size_t ws_size,
                              hipStream_t stream)
{
    const float* coords   = (const float*)d_in[0];
    const float* w1       = (const float*)d_in[1];
    const float* b1       = (const float*)d_in[2];
    const float* w2       = (const float*)d_in[3];
    const float* b2       = (const float*)d_in[4];
    const int*   gm       = (const int*)d_in[5];
    const int*   lcg      = (const int*)d_in[6];
    const int*   genes_oi = (const int*)d_in[7];

    int n_frag  = in_sizes[5];
    int n_genes = in_sizes[4];
    int gene_n  = in_sizes[7];
    int total   = out_size;
    float* out  = (float*)d_out;

    int nblk = (n_frag + HCHUNK - 1) / HCHUNK;
    int wmax = (n_frag >> 6) + n_genes + 1;            // upper bound on frag-waves
    size_t padcap = (size_t)n_frag + 64 * (size_t)n_genes + 64;

    // workspace layout
    short* w1T      = (short*)d_ws;                        // [n_genes*2000 + 64] bf16
    size_t w1T_sh   = (size_t)n_genes * 2000 + 64;
    int* counts_mat = (int*)(w1T + w1T_sh);                // [nblk][MAXG]
    int* po         = counts_mat + (size_t)nblk * MAXG;    // [MAXG+1]
    int* cursor     = po + (MAXG + 1);                     // [MAXG]
    int* cnt        = cursor + MAXG;                       // [MAXG]
    int* w2g        = cnt + MAXG;                          // [wmax]
    float* xs       = (float*)(w2g + wmax);                // [2*padcap]
    int* bins       = (int*)(xs + 2 * padcap);             // [padcap]
    size_t need = w1T_sh * sizeof(short)
                + ((size_t)nblk * MAXG + (MAXG + 1) + 2 * MAXG + wmax
                   + 3 * padcap) * sizeof(int);

    bool use_sorted = (ws_size >= need) && (n_genes <= MAXG);
    if (use_sorted) {
        int g1 = (nblk > n_genes) ? nblk : n_genes;
        hist_init_k<<<g1, HTPB, 0, stream>>>(gm, w1, w1T, n_frag, n_genes, nblk,
                                             counts_mat, out, b2, genes_oi, gene_n, total);
        scan_k<<<1, MAXG, 0, stream>>>(counts_mat, nblk, po, cursor, cnt, w2g,
                                       n_genes, wmax);
        scatter_k<<<nblk, HTPB, 0, stream>>>(gm, coords, lcg, cursor,
                                             xs, bins, n_frag, n_genes);
        int mblk = (wmax + 3) / 4;
        main_mfma_k<<<mblk, 256, 0, stream>>>(w1T, b1, w2, genes_oi, xs, bins,
                                              po, cnt, w2g, out, gene_n, wmax);
    } else {
        init_out_k<<<(total + 255) / 256, 256, 0, stream>>>(out, b2, genes_oi, gene_n, total);
        frag_naive_k<<<(n_frag + 255) / 256, 256, 0, stream>>>(coords, w1, b1, w2, gm, lcg,
                                                               genes_oi, out, gene_n, n_frag);
    }
}

// Round 11
// 45.286 us; speedup vs baseline: 1.8663x; 1.0159x over previous
//
#include <hip/hip_runtime.h>
#include <hip/hip_bf16.h>
#include <math.h>

#define NF    50              // n_frequencies
#define DEMB  10              // embedding dim
#define W1G   (4 * NF * DEMB) // 2000 floats of w1 per gene
#define MAXG  512             // max genes supported by sort path

#define HTPB   256
#define HCHUNK 4096
#define HFPT   (HCHUNK / HTPB) // 16 fragments per thread in hist/scatter

#define HPAD  11              // fp32 stride of per-wave LDS h tile
#define TKP   208             // transpose tile k-stride (bf16)

typedef __attribute__((ext_vector_type(8))) short short8v;      // 8 bf16
typedef __attribute__((ext_vector_type(4))) unsigned int uint4v;
typedef __attribute__((ext_vector_type(4))) float f32x4v;

__device__ __forceinline__ short f2bf(float f) {
    union { __hip_bfloat16 b; unsigned short u; } v;
    v.b = __float2bfloat16(f);
    return (short)v.u;
}
__device__ __forceinline__ unsigned pkbf(float lo, float hi) {
    union { __hip_bfloat162 b; unsigned u; } v;
    v.b = __float22bfloat162_rn(make_float2(lo, hi));   // .x -> low half
    return v.u;
}

// ---------------------------------------------------------------------------
// K1: per-block private histogram rows + out init with b2 + w1 transpose.
// ---------------------------------------------------------------------------
__global__ __launch_bounds__(HTPB) void hist_init_k(
    const int* __restrict__ gm, const float* __restrict__ w1,
    short* __restrict__ w1T, int n_frag, int n_genes, int nblk,
    int* __restrict__ counts_mat,                 // [nblk][MAXG]
    float* __restrict__ out, const float* __restrict__ b2,
    const int* __restrict__ genes_oi, int gene_n, int total)
{
    __shared__ int lcnt[MAXG];
    __shared__ __align__(16) short tile[DEMB][TKP];

    bool do_hist = (int)blockIdx.x < nblk;
    bool do_tr   = (int)blockIdx.x < n_genes;

    for (int t = threadIdx.x; t < MAXG; t += HTPB) lcnt[t] = 0;
    __syncthreads();

    if (do_hist) {
        int base = blockIdx.x * HCHUNK;
#pragma unroll
        for (int j = 0; j < HFPT; ++j) {
            int f = base + j * HTPB + (int)threadIdx.x;
            if (f < n_frag) atomicAdd(&lcnt[gm[f]], 1);
        }
    }

    if (do_tr) {
        const float* wg = w1 + (size_t)blockIdx.x * W1G;
        for (int e4 = threadIdx.x; e4 < W1G / 4; e4 += HTPB) {
            float4 v = ((const float4*)wg)[e4];
            int e = e4 * 4;
            int k0 = e / 10, d0 = e - k0 * 10;
#pragma unroll
            for (int c = 0; c < 4; ++c) {
                tile[d0][k0] = f2bf((&v.x)[c]);
                d0++; if (d0 == 10) { d0 = 0; k0++; }
            }
        }
    }

    // init out with broadcast b2 (grid-stride)
    int nthreads = gridDim.x * HTPB;
    for (int i = blockIdx.x * HTPB + (int)threadIdx.x; i < total; i += nthreads) {
        int col = (int)((unsigned)i % (unsigned)gene_n);
        out[i] = b2[genes_oi[col]];
    }
    // zero the small tail after w1T (over-read by kk=6 B loads)
    if (blockIdx.x == 0 && threadIdx.x < 64)
        w1T[(size_t)n_genes * 2000 + threadIdx.x] = 0;

    __syncthreads();

    if (do_hist) {
        int* row = counts_mat + (size_t)blockIdx.x * MAXG;
        for (int t = threadIdx.x; t < MAXG; t += HTPB) row[t] = lcnt[t];
    }
    if (do_tr) {
        short* og = w1T + (size_t)blockIdx.x * 2000;
        for (int o = threadIdx.x; o < 250; o += HTPB) {
            int dd = o / 25;
            int off = (o - dd * 25) * 8;
            *(short8v*)(og + dd * 200 + off) = *(const short8v*)&tile[dd][off];
        }
    }
}

// ---------------------------------------------------------------------------
// K2: reduce count matrix; scan of 64-PADDED counts; build wave->gene table.
// ---------------------------------------------------------------------------
__global__ void scan_k(const int* __restrict__ counts_mat, int nblk,
                       int* __restrict__ po, int* __restrict__ cursor,
                       int* __restrict__ cnt, int* __restrict__ w2g,
                       int n_genes, int wmax)
{
    __shared__ int buf[MAXG];
    int tid = threadIdx.x;
    int s = 0;
#pragma unroll 8
    for (int b = 0; b < nblk; ++b) s += counts_mat[(size_t)b * MAXG + tid];
    int pc = ((s + 63) >> 6) << 6;       // padded count
    buf[tid] = pc;
    __syncthreads();
    for (int d = 1; d < MAXG; d <<= 1) {
        int t = (tid >= d) ? buf[tid - d] : 0;
        __syncthreads();
        buf[tid] += t;
        __syncthreads();
    }
    int incl = buf[tid];
    if (tid < n_genes) {
        po[tid + 1] = incl;
        cursor[tid] = incl - pc;
        cnt[tid]    = s;
        int wbeg = (incl - pc) >> 6;
        int wend = incl >> 6;
        for (int w = wbeg; w < wend; ++w) w2g[w] = tid;
    }
    if (tid == 0) po[0] = 0;
    __syncthreads();
    int W = buf[n_genes - 1] >> 6;
    for (int w = W + tid; w < wmax; w += MAXG) w2g[w] = -1;
}

// ---------------------------------------------------------------------------
// K3: scatter packed records (coords, bin) into padded gene-sorted order.
// ---------------------------------------------------------------------------
__global__ __launch_bounds__(HTPB) void scatter_k(
    const int* __restrict__ gm, const float* __restrict__ coords,
    const int* __restrict__ lcg, int* __restrict__ cursor,
    float* __restrict__ xs, int* __restrict__ bins,
    int n_frag, int n_genes)
{
    __shared__ int lcnt[MAXG];
    __shared__ int lbase[MAXG];
    for (int t = threadIdx.x; t < MAXG; t += HTPB) lcnt[t] = 0;
    __syncthreads();

    int base = blockIdx.x * HCHUNK;
    int g[HFPT], lr[HFPT];
#pragma unroll
    for (int j = 0; j < HFPT; ++j) {
        int f = base + j * HTPB + (int)threadIdx.x;
        if (f < n_frag) {
            g[j]  = gm[f];
            lr[j] = atomicAdd(&lcnt[g[j]], 1);
        } else {
            g[j] = -1;
        }
    }
    __syncthreads();
    for (int t = threadIdx.x; t < MAXG; t += HTPB) {
        int c = lcnt[t];
        lbase[t] = c ? atomicAdd(&cursor[t], c) : 0;
    }
    __syncthreads();
#pragma unroll
    for (int j = 0; j < HFPT; ++j) {
        if (g[j] >= 0) {
            int f = base + j * HTPB + (int)threadIdx.x;
            int pos = lbase[g[j]] + lr[j];
            float2 xy = ((const float2*)coords)[f];
            xs[2 * pos + 0] = xy.x;
            xs[2 * pos + 1] = xy.y;
            bins[pos] = lcg[f];
        }
    }
}

// ---------------------------------------------------------------------------
// K4: main (MFMA v4) — register-diet restructure of the r10-passing kernel.
//  - kk-outer / m-inner loop; freq operands read from LDS per kk (float4),
//    no frv[7] register bank (-28 VGPR).
//  - ax[4]/ay[4] shfl'd ONCE before the loop (8 bpermutes total).
//  - kk==6 pad: lane-uniform (q>=1) -> zero the whole afrag.
//  - B: 7 direct 16B loads from bf16 w1T (L1-hot across a gene's waves).
//  - Epilogue: per-wave LDS h-transpose (d<10 write guard), lane owns its
//    fragment, dot with w2, one atomicAdd.
// ---------------------------------------------------------------------------
__global__ __launch_bounds__(256, 4) void main_mfma_k(
    const short* __restrict__ w1T, const float* __restrict__ b1,
    const float* __restrict__ w2, const int* __restrict__ genes_oi,
    const float* __restrict__ xs, const int* __restrict__ bins,
    const int* __restrict__ po, const int* __restrict__ cnt,
    const int* __restrict__ w2g, float* __restrict__ out,
    int gene_n, int wmax)
{
    __shared__ __align__(16) float fr_ext[116];     // fr[i mod 50]
    __shared__ __align__(16) float hb_all[4][64 * HPAD];

    if (threadIdx.x < 116) {
        int i = threadIdx.x;
        int im = (i < 50) ? i : ((i < 100) ? i - 50 : i - 100);
        float ex = (-2.0f * (float)(im + 1) / (float)NF) * 9.965784284662087f; // log2(1000)
        fr_ext[i] = exp2f(ex) * 0.15915494309189535f;   // base/(2*pi): revolutions
    }
    __syncthreads();

    int wid  = threadIdx.x >> 6;
    int lane = threadIdx.x & 63;
    int fw   = blockIdx.x * 4 + wid;          // frag-wave index

    int g = (fw < wmax) ? w2g[fw] : -1;
    g = __builtin_amdgcn_readfirstlane(g);
    if (g < 0) return;                        // after the only barrier

    int d  = lane & 15;                       // output dim / B col
    int q  = lane >> 4;                       // k-group
    int dc = (d < 10) ? d : 9;                // clamped dim (cols 10-15 junk)

    int start = po[g];
    int count = cnt[g];
    int pos   = fw * 64 + lane;
    bool valid = (pos - start) < count;
    float2 xy = valid ? ((const float2*)xs)[pos] : make_float2(0.0f, 0.0f);
    int bin_own = valid ? bins[pos] : 0;
    int col_own = (int)((unsigned)bin_own % (unsigned)gene_n);

    // ---- B fragments: 7 direct 16B loads from transposed w1T ----
    const short* bp = w1T + (size_t)g * 2000 + dc * 200 + q * 8;
    short8v breg[7];
#pragma unroll
    for (int kk = 0; kk < 7; ++kk)
        breg[kk] = *(const short8v*)(bp + kk * 32);

    // ---- hoisted row-coord broadcasts (8 bpermutes total) ----
    float ax[4], ay[4];
#pragma unroll
    for (int m = 0; m < 4; ++m) {
        int srcA = m * 16 + d;                // fragment whose A-row this lane supplies
        ax[m] = __shfl(xy.x, srcA);
        ay[m] = __shfl(xy.y, srcA);
    }

    // ---- accumulators init with b1 ----
    float b1v = b1[(size_t)g * DEMB + dc];
    f32x4v acc[4];
#pragma unroll
    for (int m = 0; m < 4; ++m) { acc[m][0] = b1v; acc[m][1] = b1v; acc[m][2] = b1v; acc[m][3] = b1v; }

    // ---- MFMA loop: kk outer, m inner; freq operands from LDS per kk ----
#pragma unroll
    for (int kk = 0; kk < 7; ++kk) {
        float4 fv4 = *(const float4*)&fr_ext[16 * kk + 4 * q];
#pragma unroll
        for (int m = 0; m < 4; ++m) {
            uint4v au;
#pragma unroll
            for (int jj = 0; jj < 4; ++jj) {
                int idx = 16 * kk + 4 * q + jj;        // k = 2*idx; idx<50 -> coord0
                float fv = (&fv4.x)[jj];
                float xv = (idx < 50) ? ax[m] : ay[m];
                float r = xv * fv; r -= rintf(r);      // revolutions in [-0.5,0.5]
                au[jj] = pkbf(__builtin_amdgcn_sinf(r), __builtin_amdgcn_cosf(r));
            }
            if (kk == 6 && q > 0) {                    // k>=200 pad (lane-uniform)
                au[0] = 0; au[1] = 0; au[2] = 0; au[3] = 0;
            }
            short8v afrag = __builtin_bit_cast(short8v, au);
            acc[m] = __builtin_amdgcn_mfma_f32_16x16x32_bf16(afrag, breg[kk], acc[m], 0, 0, 0);
        }
    }

    // ---- epilogue: per-wave LDS h-transpose; lane owns its fragment ----
    float* hb = hb_all[wid];
    if (d < 10) {                              // junk cols must not write (r9 bug)
#pragma unroll
        for (int m = 0; m < 4; ++m)
#pragma unroll
            for (int r = 0; r < 4; ++r)
                hb[(m * 16 + q * 4 + r) * HPAD + d] = acc[m][r];
    }

    int gi = genes_oi[col_own];
    const float* w2r = w2 + (size_t)gi * DEMB;
    float sum = 0.0f;
#pragma unroll
    for (int p2 = 0; p2 < 5; ++p2) {
        float2 wv = *(const float2*)(w2r + 2 * p2);
        float h0 = hb[lane * HPAD + 2 * p2];
        float h1 = hb[lane * HPAD + 2 * p2 + 1];
        sum += wv.x / (1.0f + __expf(-h0));
        sum += wv.y / (1.0f + __expf(-h1));
    }
    if (valid) atomicAdd(&out[bin_own], sum);
}

// ---------------------------------------------------------------------------
// Fallback (workspace too small): one thread per fragment, non-uniform gene
// ---------------------------------------------------------------------------
__global__ __launch_bounds__(256) void frag_naive_k(
    const float* __restrict__ coords, const float* __restrict__ w1,
    const float* __restrict__ b1, const float* __restrict__ w2,
    const int* __restrict__ gm, const int* __restrict__ lcg,
    const int* __restrict__ genes_oi, float* __restrict__ out,
    int gene_n, int n_frag)
{
    __shared__ float fr[NF];
    if (threadIdx.x < NF) {
        float ex = (-2.0f * (float)(threadIdx.x + 1) / (float)NF) * 9.965784284662087f;
        fr[threadIdx.x] = exp2f(ex) * 0.15915494309189535f;
    }
    __syncthreads();

    int f = blockIdx.x * blockDim.x + threadIdx.x;
    if (f >= n_frag) return;
    int g = gm[f];
    const float* wrow  = w1 + (size_t)g * W1G;
    const float* b1row = b1 + (size_t)g * DEMB;
    float x0 = coords[2 * f + 0];
    float x1 = coords[2 * f + 1];

    float h[DEMB];
#pragma unroll
    for (int d = 0; d < DEMB; ++d) h[d] = b1row[d];
#pragma unroll 2
    for (int i = 0; i < NF; ++i) {
        float fv = fr[i];
        float r0 = x0 * fv; r0 -= rintf(r0);
        float r1 = x1 * fv; r1 -= rintf(r1);
        float s0 = __builtin_amdgcn_sinf(r0), c0 = __builtin_amdgcn_cosf(r0);
        float s1 = __builtin_amdgcn_sinf(r1), c1 = __builtin_amdgcn_cosf(r1);
        const float* wa = wrow + (2 * i) * DEMB;
        const float* wb = wrow + (2 * NF + 2 * i) * DEMB;
#pragma unroll
        for (int d = 0; d < DEMB; ++d) {
            h[d] += s0 * wa[d] + c0 * wa[DEMB + d] + s1 * wb[d] + c1 * wb[DEMB + d];
        }
    }
    int bin = lcg[f];
    int col = (int)((unsigned)bin % (unsigned)gene_n);
    const float* w2row = w2 + (size_t)genes_oi[col] * DEMB;
    float sum = 0.0f;
#pragma unroll
    for (int d = 0; d < DEMB; ++d) {
        float sg = 1.0f / (1.0f + __expf(-h[d]));
        sum += sg * w2row[d];
    }
    atomicAdd(&out[bin], sum);
}

__global__ void init_out_k(float* __restrict__ out, const float* __restrict__ b2,
                           const int* __restrict__ genes_oi, int gene_n, int total)
{
    int i = blockIdx.x * blockDim.x + threadIdx.x;
    if (i < total) {
        int col = (int)((unsigned)i % (unsigned)gene_n);
        out[i] = b2[genes_oi[col]];
    }
}

// ---------------------------------------------------------------------------
extern "C" void kernel_launch(void* const* d_in, const int* in_sizes, int n_in,
                              void* d_out, int out_size, void* d_ws, size_t ws_size,
                              hipStream_t stream)
{
    const float* coords   = (const float*)d_in[0];
    const float* w1       = (const float*)d_in[1];
    const float* b1       = (const float*)d_in[2];
    const float* w2       = (const float*)d_in[3];
    const float* b2       = (const float*)d_in[4];
    const int*   gm       = (const int*)d_in[5];
    const int*   lcg      = (const int*)d_in[6];
    const int*   genes_oi = (const int*)d_in[7];

    int n_frag  = in_sizes[5];
    int n_genes = in_sizes[4];
    int gene_n  = in_sizes[7];
    int total   = out_size;
    float* out  = (float*)d_out;

    int nblk = (n_frag + HCHUNK - 1) / HCHUNK;
    int wmax = (n_frag >> 6) + n_genes + 1;            // upper bound on frag-waves
    size_t padcap = (size_t)n_frag + 64 * (size_t)n_genes + 64;

    // workspace layout
    short* w1T      = (short*)d_ws;                        // [n_genes*2000 + 64] bf16
    size_t w1T_sh   = (size_t)n_genes * 2000 + 64;
    int* counts_mat = (int*)(w1T + w1T_sh);                // [nblk][MAXG]
    int* po         = counts_mat + (size_t)nblk * MAXG;    // [MAXG+1]
    int* cursor     = po + (MAXG + 1);                     // [MAXG]
    int* cnt        = cursor + MAXG;                       // [MAXG]
    int* w2g        = cnt + MAXG;                          // [wmax]
    float* xs       = (float*)(w2g + wmax);                // [2*padcap]
    int* bins       = (int*)(xs + 2 * padcap);             // [padcap]
    size_t need = w1T_sh * sizeof(short)
                + ((size_t)nblk * MAXG + (MAXG + 1) + 2 * MAXG + wmax
                   + 3 * padcap) * sizeof(int);

    bool use_sorted = (ws_size >= need) && (n_genes <= MAXG);
    if (use_sorted) {
        int g1 = (nblk > n_genes) ? nblk : n_genes;
        hist_init_k<<<g1, HTPB, 0, stream>>>(gm, w1, w1T, n_frag, n_genes, nblk,
                                             counts_mat, out, b2, genes_oi, gene_n, total);
        scan_k<<<1, MAXG, 0, stream>>>(counts_mat, nblk, po, cursor, cnt, w2g,
                                       n_genes, wmax);
        scatter_k<<<nblk, HTPB, 0, stream>>>(gm, coords, lcg, cursor,
                                             xs, bins, n_frag, n_genes);
        int mblk = (wmax + 3) / 4;
        main_mfma_k<<<mblk, 256, 0, stream>>>(w1T, b1, w2, genes_oi, xs, bins,
                                              po, cnt, w2g, out, gene_n, wmax);
    } else {
        init_out_k<<<(total + 255) / 256, 256, 0, stream>>>(out, b2, genes_oi, gene_n, total);
        frag_naive_k<<<(n_frag + 255) / 256, 256, 0, stream>>>(coords, w1, b1, w2, gm, lcg,
                                                               genes_oi, out, gene_n, n_frag);
    }
}